// Round 4
// baseline (215.687 us; speedup 1.0000x reference)
//
#include <hip/hip_runtime.h>

// PositionLossVal: offset [4,18,512,512] f32, optical_flow [4,8,512,512] f32 -> scalar f32.
// Per pixel: x=off[i], y=off[i+9] (i<9); u=flow[j], v=flow[j+1] (j<4).
// md = inside ? perp : min(d1,d2); min over j, mean over i, sum over b,h,w, /(h*w).
// min over j in squared domain -> 1 sqrt per (pixel,i).
// inside: x0*(x0-u)<=0 with x0 = u*(x^2+v*y)/uu  <=>  w*(w-uu)<=0, w = x^2+v*y  (u^2>0;
//         u==0 gives ins=0=inside in ref, measure-zero for random-normal inputs).
// Single fused kernel: last-block-done reduction (rocPRIM pattern), counter zeroed by a
// 4-byte memset node each call (graph-capture-safe; d_ws is poisoned 0xAA before timing).

#define HW_BITS 18
#define HW_ (1 << HW_BITS)          // 512*512
#define NOFF 9
#define NFLOW 4
#define NPIX (4 * HW_)              // 1,048,576 pixels
#define PPT 4                       // pixels per thread (float4 loads)
#define BLK 256
#define GRID1 (NPIX / PPT / BLK)    // 1024 blocks
#define CNT_OFF 8192                // byte offset of the done-counter in d_ws

__global__ __launch_bounds__(BLK, 4)   // cap VGPR at 128 -> 4 waves/SIMD
void pos_loss_fused(const float* __restrict__ off, const float* __restrict__ flow,
                    float* __restrict__ partial, unsigned int* __restrict__ cnt,
                    float* __restrict__ out)
{
    const int t  = blockIdx.x * BLK + threadIdx.x;
    const int g  = t * PPT;                          // 4 consecutive pixels, same image
    const int b  = g >> HW_BITS;
    const int hw = g & (HW_ - 1);
    const float* offb = off  + ((size_t)b * (2 * NOFF)) * HW_ + hw;
    const float* flb  = flow + ((size_t)b * 8) * HW_ + hw;

    // Flow channels 0..4 as float4 (1KB per wave-instruction).
    float4 f4[NFLOW + 1];
#pragma unroll
    for (int j = 0; j <= NFLOW; ++j)
        f4[j] = *reinterpret_cast<const float4*>(flb + (size_t)j * HW_);

    // Per-(px,j) invariants: uu = u^2+v^2, r = 1/uu.
    float uu_[PPT][NFLOW], r_[PPT][NFLOW];
#pragma unroll
    for (int j = 0; j < NFLOW; ++j) {
        const float up[PPT] = {f4[j].x, f4[j].y, f4[j].z, f4[j].w};
        const float vp[PPT] = {f4[j + 1].x, f4[j + 1].y, f4[j + 1].z, f4[j + 1].w};
#pragma unroll
        for (int p = 0; p < PPT; ++p) {
            const float uu = fmaf(up[p], up[p], vp[p] * vp[p]);
            uu_[p][j] = uu;
            r_[p][j]  = __builtin_amdgcn_rcpf(uu);
        }
    }

    float acc = 0.f;
#pragma unroll
    for (int i = 0; i < NOFF; ++i) {
        // Loads issued per-iteration; unrolled loop lets the scheduler pipeline them.
        const float4 x4 = *reinterpret_cast<const float4*>(offb + (size_t)i * HW_);
        const float4 y4 = *reinterpret_cast<const float4*>(offb + (size_t)(i + NOFF) * HW_);
        const float xp[PPT] = {x4.x, x4.y, x4.z, x4.w};
        const float yp[PPT] = {y4.x, y4.y, y4.z, y4.w};
#pragma unroll
        for (int p = 0; p < PPT; ++p) {
            const float x  = xp[p], y = yp[p];
            const float x2 = x * x;
            const float d1sq = fmaf(y, y, x2);
            float m2 = 1e30f;
#pragma unroll
            for (int j = 0; j < NFLOW; ++j) {
                const float u = (p == 0) ? f4[j].x : (p == 1) ? f4[j].y : (p == 2) ? f4[j].z : f4[j].w;
                const float v = (p == 0) ? f4[j + 1].x : (p == 1) ? f4[j + 1].y : (p == 2) ? f4[j + 1].z : f4[j + 1].w;
                const float w   = fmaf(v, y, x2);                 // x^2 + v*y
                const float ins = w * (w - uu_[p][j]);            // sign == x0*(x0-u)
                const float tt  = fmaf(v, x, -(u * y));           // v*x - u*y
                const float p2  = (tt * tt) * r_[p][j];
                const float dx = x - u, dy = y - v;
                const float d2sq = fmaf(dy, dy, dx * dx);
                const float e2  = fminf(d1sq, d2sq);
                const float md2 = (ins <= 0.f) ? p2 : e2;
                m2 = fminf(m2, md2);
            }
            acc += __builtin_amdgcn_sqrtf(m2);
        }
    }

    // Block reduction: wave64 shuffle tree -> LDS -> one partial per block.
#pragma unroll
    for (int o = 32; o > 0; o >>= 1) acc += __shfl_down(acc, o, 64);
    __shared__ float sm[BLK / 64];
    const int lane = threadIdx.x & 63, wid = threadIdx.x >> 6;
    if (lane == 0) sm[wid] = acc;
    __syncthreads();

    __shared__ int s_last;
    if (threadIdx.x == 0) {
        // Coherent (device-scope) store of this block's partial, then signal.
        atomicExch(&partial[blockIdx.x], sm[0] + sm[1] + sm[2] + sm[3]);
        __threadfence();
        const unsigned old = atomicAdd(cnt, 1u);
        s_last = (old == GRID1 - 1);
    }
    __syncthreads();

    if (s_last) {
        __threadfence();
        float s = 0.f;
#pragma unroll
        for (int k = 0; k < GRID1 / BLK; ++k)
            s += atomicAdd(&partial[k * BLK + (int)threadIdx.x], 0.0f);  // coherent load
#pragma unroll
        for (int o = 32; o > 0; o >>= 1) s += __shfl_down(s, o, 64);
        if (lane == 0) sm[wid] = s;
        __syncthreads();
        if (threadIdx.x == 0)
            out[0] = (sm[0] + sm[1] + sm[2] + sm[3]) * (1.0f / (9.0f * (float)HW_));
    }
}

extern "C" void kernel_launch(void* const* d_in, const int* in_sizes, int n_in,
                              void* d_out, int out_size, void* d_ws, size_t ws_size,
                              hipStream_t stream) {
    const float* offset = (const float*)d_in[0];   // [4,18,512,512]
    const float* flow   = (const float*)d_in[1];   // [4,8,512,512]
    float* partial = (float*)d_ws;                 // GRID1 floats
    unsigned int* cnt = (unsigned int*)((char*)d_ws + CNT_OFF);
    float* out = (float*)d_out;

    hipMemsetAsync(cnt, 0, sizeof(unsigned int), stream);  // capture-safe memset node
    pos_loss_fused<<<GRID1, BLK, 0, stream>>>(offset, flow, partial, cnt, out);
}

// Round 5
// 80.924 us; speedup vs baseline: 2.6653x; 2.6653x over previous
//
#include <hip/hip_runtime.h>

// PositionLossVal: offset [4,18,512,512] f32, optical_flow [4,8,512,512] f32 -> scalar f32.
// Per pixel: x=off[i], y=off[i+9] (i<9); u=flow[j], v=flow[j+1] (j<4).
// md = inside ? perp : min(d1,d2); min over j, mean over i, sum over b,h,w, /(h*w).
// min over j in squared domain -> 1 sqrt per (pixel,i).
// inside: x0*(x0-u)<=0, x0 = u*(x^2+v*y)/uu  <=>  w*(w-uu)<=0 with w = x^2+v*y.
// Fused single kernel: last-block-done reduction; counter zeroed by 4-byte memset node.
// R4 lesson: PPT=4 + 128-VGPR cap => 1.1KB/thread scratch spill (WRITE_SIZE 289MB).
// PPT=2 fits the cap (R3-proven); offset loads issued per-i to keep peak pressure low.

#define HW_BITS 18
#define HW_ (1 << HW_BITS)          // 512*512
#define NOFF 9
#define NFLOW 4
#define NPIX (4 * HW_)              // 1,048,576 pixels
#define PPT 2                       // pixels per thread (float2 loads)
#define BLK 256
#define GRID1 (NPIX / PPT / BLK)    // 2048 blocks
#define CNT_OFF 16384               // byte offset of the done-counter in d_ws

__global__ __launch_bounds__(BLK, 4)   // cap VGPR at 128 -> >=4 waves/SIMD (PPT=2 fits)
void pos_loss_fused(const float* __restrict__ off, const float* __restrict__ flow,
                    float* __restrict__ partial, unsigned int* __restrict__ cnt,
                    float* __restrict__ out)
{
    const int t  = blockIdx.x * BLK + threadIdx.x;
    const int g  = t * PPT;                          // 2 consecutive pixels, same image
    const int b  = g >> HW_BITS;
    const int hw = g & (HW_ - 1);
    const float* offb = off  + ((size_t)b * (2 * NOFF)) * HW_ + hw;
    const float* flb  = flow + ((size_t)b * 8) * HW_ + hw;

    // Flow channels 0..4 as float2 (512B per wave-instruction), live across the i-loop.
    float2 f2[NFLOW + 1];
#pragma unroll
    for (int j = 0; j <= NFLOW; ++j)
        f2[j] = *reinterpret_cast<const float2*>(flb + (size_t)j * HW_);

    // Per-(px,j) invariants: uu = u^2+v^2, r = 1/uu.
    float uu_[PPT][NFLOW], r_[PPT][NFLOW];
#pragma unroll
    for (int j = 0; j < NFLOW; ++j) {
        const float up[PPT] = {f2[j].x, f2[j].y};
        const float vp[PPT] = {f2[j + 1].x, f2[j + 1].y};
#pragma unroll
        for (int p = 0; p < PPT; ++p) {
            const float uu = fmaf(up[p], up[p], vp[p] * vp[p]);
            uu_[p][j] = uu;
            r_[p][j]  = __builtin_amdgcn_rcpf(uu);
        }
    }

    float acc = 0.f;
#pragma unroll
    for (int i = 0; i < NOFF; ++i) {
        // Loads issued per-i; fully-unrolled loop lets the scheduler hoist/pipeline them
        // without keeping all 18 channels live at once (VGPR pressure).
        const float2 x2v = *reinterpret_cast<const float2*>(offb + (size_t)i * HW_);
        const float2 y2v = *reinterpret_cast<const float2*>(offb + (size_t)(i + NOFF) * HW_);
        const float xp[PPT] = {x2v.x, x2v.y};
        const float yp[PPT] = {y2v.x, y2v.y};
#pragma unroll
        for (int p = 0; p < PPT; ++p) {
            const float x  = xp[p], y = yp[p];
            const float x2 = x * x;
            const float d1sq = fmaf(y, y, x2);
            float m2 = 1e30f;
#pragma unroll
            for (int j = 0; j < NFLOW; ++j) {
                const float u = (p == 0) ? f2[j].x : f2[j].y;
                const float v = (p == 0) ? f2[j + 1].x : f2[j + 1].y;
                const float w   = fmaf(v, y, x2);                 // x^2 + v*y
                const float ins = w * (w - uu_[p][j]);            // sign == x0*(x0-u)
                const float tt  = fmaf(v, x, -(u * y));           // v*x - u*y
                const float p2  = (tt * tt) * r_[p][j];
                const float dx = x - u, dy = y - v;
                const float d2sq = fmaf(dy, dy, dx * dx);
                const float e2  = fminf(d1sq, d2sq);
                const float md2 = (ins <= 0.f) ? p2 : e2;
                m2 = fminf(m2, md2);
            }
            acc += __builtin_amdgcn_sqrtf(m2);
        }
    }

    // Block reduction: wave64 shuffle tree -> LDS -> one partial per block.
#pragma unroll
    for (int o = 32; o > 0; o >>= 1) acc += __shfl_down(acc, o, 64);
    __shared__ float sm[BLK / 64];
    const int lane = threadIdx.x & 63, wid = threadIdx.x >> 6;
    if (lane == 0) sm[wid] = acc;
    __syncthreads();

    __shared__ int s_last;
    if (threadIdx.x == 0) {
        // Device-scope (coherent) store of this block's partial, then signal done.
        atomicExch(&partial[blockIdx.x], sm[0] + sm[1] + sm[2] + sm[3]);
        __threadfence();
        const unsigned old = atomicAdd(cnt, 1u);
        s_last = (old == GRID1 - 1);
    }
    __syncthreads();

    if (s_last) {
        __threadfence();
        float s = 0.f;
#pragma unroll
        for (int k = 0; k < GRID1 / BLK; ++k)
            s += atomicAdd(&partial[k * BLK + (int)threadIdx.x], 0.0f);  // coherent load
#pragma unroll
        for (int o = 32; o > 0; o >>= 1) s += __shfl_down(s, o, 64);
        if (lane == 0) sm[wid] = s;
        __syncthreads();
        if (threadIdx.x == 0)
            out[0] = (sm[0] + sm[1] + sm[2] + sm[3]) * (1.0f / (9.0f * (float)HW_));
    }
}

extern "C" void kernel_launch(void* const* d_in, const int* in_sizes, int n_in,
                              void* d_out, int out_size, void* d_ws, size_t ws_size,
                              hipStream_t stream) {
    const float* offset = (const float*)d_in[0];   // [4,18,512,512]
    const float* flow   = (const float*)d_in[1];   // [4,8,512,512]
    float* partial = (float*)d_ws;                 // GRID1 floats (8 KB)
    unsigned int* cnt = (unsigned int*)((char*)d_ws + CNT_OFF);
    float* out = (float*)d_out;

    hipMemsetAsync(cnt, 0, sizeof(unsigned int), stream);  // capture-safe memset node
    pos_loss_fused<<<GRID1, BLK, 0, stream>>>(offset, flow, partial, cnt, out);
}

// Round 6
// 27.141 us; speedup vs baseline: 7.9470x; 2.9816x over previous
//
#include <hip/hip_runtime.h>

// PositionLossVal: offset [4,18,512,512] f32, optical_flow [4,8,512,512] f32 -> scalar f32.
// Per pixel: x=off[i], y=off[i+9] (i<9); u=flow[j], v=flow[j+1] (j<4).
// md = inside ? perp : min(d1,d2); min over j, mean over i, sum over b,h,w, /(h*w).
// min over j in squared domain -> 1 sqrt per (pixel,i).
// inside: x0*(x0-u)<=0, x0 = u*(x^2+v*y)/uu  <=>  w*(w-uu)<=0 with w = x^2+v*y.
//
// R5 lesson: fused last-block tail = 2048 serialized same-address device-scope atomics
// (cross-XCD coherence point) + per-block threadfence => +60us. Two kernels it is.
// R4 lesson: PPT=4 under the 128-VGPR cap spills 1.1KB/thread. PPT=2 fits (64 VGPR).
// This round: main kernel has NO barrier / NO LDS (per-wave shuffle reduce, one store
// per wave); final reduce is a single 1024-thread block.

#define HW_BITS 18
#define HW_ (1 << HW_BITS)          // 512*512
#define NOFF 9
#define NFLOW 4
#define NPIX (4 * HW_)              // 1,048,576 pixels
#define PPT 2                       // pixels per thread (float2 loads)
#define BLK 256
#define GRID1 (NPIX / PPT / BLK)    // 2048 blocks
#define NPART (GRID1 * (BLK / 64))  // 8192 wave partials
#define RBLK 1024

__global__ __launch_bounds__(BLK, 4)   // 128-VGPR cap; PPT=2 compiles to ~64 VGPR, no spill
void pos_loss_main(const float* __restrict__ off, const float* __restrict__ flow,
                   float* __restrict__ partial)
{
    const int t  = blockIdx.x * BLK + threadIdx.x;
    const int g  = t * PPT;                          // 2 consecutive pixels, same image
    const int b  = g >> HW_BITS;
    const int hw = g & (HW_ - 1);
    const float* offb = off  + ((size_t)b * (2 * NOFF)) * HW_ + hw;
    const float* flb  = flow + ((size_t)b * 8) * HW_ + hw;

    // Flow channels 0..4 as float2 (512B per wave-instruction), live across the i-loop.
    float2 f2[NFLOW + 1];
#pragma unroll
    for (int j = 0; j <= NFLOW; ++j)
        f2[j] = *reinterpret_cast<const float2*>(flb + (size_t)j * HW_);

    // Per-(px,j) invariants: uu = u^2+v^2, r = 1/uu.
    float uu_[PPT][NFLOW], r_[PPT][NFLOW];
#pragma unroll
    for (int j = 0; j < NFLOW; ++j) {
        const float up[PPT] = {f2[j].x, f2[j].y};
        const float vp[PPT] = {f2[j + 1].x, f2[j + 1].y};
#pragma unroll
        for (int p = 0; p < PPT; ++p) {
            const float uu = fmaf(up[p], up[p], vp[p] * vp[p]);
            uu_[p][j] = uu;
            r_[p][j]  = __builtin_amdgcn_rcpf(uu);
        }
    }

    float acc = 0.f;
#pragma unroll
    for (int i = 0; i < NOFF; ++i) {
        // Loads issued per-i; full unroll lets the scheduler pipeline them under the
        // register budget without keeping all 18 channels live at once.
        const float2 x2v = *reinterpret_cast<const float2*>(offb + (size_t)i * HW_);
        const float2 y2v = *reinterpret_cast<const float2*>(offb + (size_t)(i + NOFF) * HW_);
        const float xp[PPT] = {x2v.x, x2v.y};
        const float yp[PPT] = {y2v.x, y2v.y};
#pragma unroll
        for (int p = 0; p < PPT; ++p) {
            const float x  = xp[p], y = yp[p];
            const float x2 = x * x;
            const float d1sq = fmaf(y, y, x2);
            float m2 = 1e30f;
#pragma unroll
            for (int j = 0; j < NFLOW; ++j) {
                const float u = (p == 0) ? f2[j].x : f2[j].y;
                const float v = (p == 0) ? f2[j + 1].x : f2[j + 1].y;
                const float w   = fmaf(v, y, x2);                 // x^2 + v*y
                const float ins = w * (w - uu_[p][j]);            // sign == x0*(x0-u)
                const float tt  = fmaf(v, x, -(u * y));           // v*x - u*y
                const float p2  = (tt * tt) * r_[p][j];
                const float dx = x - u, dy = y - v;
                const float d2sq = fmaf(dy, dy, dx * dx);
                const float e2  = fminf(d1sq, d2sq);
                const float md2 = (ins <= 0.f) ? p2 : e2;
                m2 = fminf(m2, md2);
            }
            acc += __builtin_amdgcn_sqrtf(m2);
        }
    }

    // Per-wave shuffle reduce; NO __syncthreads, NO LDS — waves retire independently.
#pragma unroll
    for (int o = 32; o > 0; o >>= 1) acc += __shfl_down(acc, o, 64);
    if ((threadIdx.x & 63) == 0)
        partial[blockIdx.x * (BLK / 64) + (threadIdx.x >> 6)] = acc;
}

__global__ __launch_bounds__(RBLK)
void pos_loss_reduce(const float* __restrict__ partial, float* __restrict__ out)
{
    float s = 0.f;
#pragma unroll
    for (int k = 0; k < NPART / RBLK; ++k)          // 8 coalesced loads
        s += partial[k * RBLK + (int)threadIdx.x];
#pragma unroll
    for (int o = 32; o > 0; o >>= 1) s += __shfl_down(s, o, 64);
    __shared__ float sm[RBLK / 64];                 // 16 wave sums
    const int lane = threadIdx.x & 63, wid = threadIdx.x >> 6;
    if (lane == 0) sm[wid] = s;
    __syncthreads();
    if (wid == 0) {
        float v = (lane < RBLK / 64) ? sm[lane] : 0.f;
#pragma unroll
        for (int o = 8; o > 0; o >>= 1) v += __shfl_down(v, o, 64);
        if (lane == 0)
            out[0] = v * (1.0f / (9.0f * (float)HW_));
    }
}

extern "C" void kernel_launch(void* const* d_in, const int* in_sizes, int n_in,
                              void* d_out, int out_size, void* d_ws, size_t ws_size,
                              hipStream_t stream) {
    const float* offset = (const float*)d_in[0];   // [4,18,512,512]
    const float* flow   = (const float*)d_in[1];   // [4,8,512,512]
    float* partial = (float*)d_ws;                 // NPART floats (32 KB), fully rewritten
    float* out     = (float*)d_out;                // 1 float

    pos_loss_main<<<GRID1, BLK, 0, stream>>>(offset, flow, partial);
    pos_loss_reduce<<<1, RBLK, 0, stream>>>(partial, out);
}